// Round 7
// baseline (202.025 us; speedup 1.0000x reference)
//
#include <hip/hip_runtime.h>
#include <stdint.h>

// DPS_55336358642719
// in[0]: x_high  (8,3,1024,1024) f32
// in[1]: scores  (8,16,16)       f32
// out:   patches (128,3,128,128) f32
//
// ws layout: counts[8][16][256] as uint32  (131072 bytes)
//
// NOTE: measured harness floor is ~145-150 us of fillBufferAligned re-poison
// (402 MB @ ~84% HBM peak) per timed iteration — not addressable from here.

#define NSAMP 500
#define DDIM  256

// ---------------- threefry2x32 (JAX-exact, key = seed 42) ----------------
__device__ __forceinline__ void threefry2x32_0_42(uint32_t x0, uint32_t x1,
                                                  uint32_t& o0, uint32_t& o1) {
  const uint32_t k0 = 0u, k1 = 42u;
  const uint32_t k2 = k0 ^ k1 ^ 0x1BD11BDAu;
  x0 += k0; x1 += k1;
#define TF_ROUND(r) { x0 += x1; x1 = (x1 << (r)) | (x1 >> (32 - (r))); x1 ^= x0; }
  TF_ROUND(13) TF_ROUND(15) TF_ROUND(26) TF_ROUND(6)
  x0 += k1; x1 += k2 + 1u;
  TF_ROUND(17) TF_ROUND(29) TF_ROUND(16) TF_ROUND(24)
  x0 += k2; x1 += k0 + 2u;
  TF_ROUND(13) TF_ROUND(15) TF_ROUND(26) TF_ROUND(6)
  x0 += k0; x1 += k1 + 3u;
  TF_ROUND(17) TF_ROUND(29) TF_ROUND(16) TF_ROUND(24)
  x0 += k1; x1 += k2 + 4u;
  TF_ROUND(13) TF_ROUND(15) TF_ROUND(26) TF_ROUND(6)
  x0 += k2; x1 += k0 + 5u;
#undef TF_ROUND
  o0 = x0; o1 = x1;
}

// XLA's ErfInv32 (Giles polynomial), fp-contract off for fidelity
__device__ __forceinline__ float xla_erfinv(float x) {
#pragma clang fp contract(off)
  float w = -log1pf(-x * x);
  float p;
  if (w < 5.0f) {
    w = w - 2.5f;
    p = 2.81022636e-08f;
    p = 3.43273939e-07f + p * w;
    p = -3.5233877e-06f + p * w;
    p = -4.39150654e-06f + p * w;
    p = 0.00021858087f + p * w;
    p = -0.00125372503f + p * w;
    p = -0.00417768164f + p * w;
    p = 0.246640727f + p * w;
    p = 1.50140941f + p * w;
  } else {
    w = sqrtf(w) - 3.0f;
    p = -0.000200214257f;
    p = 0.000100950558f + p * w;
    p = 0.00134934322f + p * w;
    p = -0.00367342844f + p * w;
    p = 0.00573950773f + p * w;
    p = -0.0076224613f + p * w;
    p = 0.00943887047f + p * w;
    p = 1.00167406f + p * w;
    p = 2.83297682f + p * w;
  }
  return p * x;
}

// One block = one (b, sample). Thread d computes perturbed value for index d;
// rank via single u64-key compare (value-monotone u32 | inverted index), which
// reproduces top_k's stable tie-break exactly; histogram via atomics.
__global__ void __launch_bounds__(256) topk_kernel(const float* __restrict__ scores,
                                                   uint32_t* __restrict__ counts) {
#pragma clang fp contract(off)
  const int gs = blockIdx.x;          // b*NSAMP + n
  const int b = gs / NSAMP;
  const int n = gs - b * NSAMP;
  const int d = threadIdx.x;
  const int lane = d & 63, wv = d >> 6;

  __shared__ __align__(16) unsigned long long pk[DDIM];
  __shared__ float wmx[4], wmn[4];
  __shared__ int wtot[4];

  const float sc = scores[b * DDIM + d];

  // block min/max of scores: wave shuffles + tiny LDS combine (exact ops)
  float mx = sc, mn = sc;
  for (int off = 32; off > 0; off >>= 1) {
    mx = fmaxf(mx, __shfl_xor(mx, off));
    mn = fminf(mn, __shfl_xor(mn, off));
  }
  if (lane == 0) { wmx[wv] = mx; wmn[wv] = mn; }
  __syncthreads();
  mx = fmaxf(fmaxf(wmx[0], wmx[1]), fmaxf(wmx[2], wmx[3]));
  mn = fminf(fminf(wmn[0], wmn[1]), fminf(wmn[2], wmn[3]));
  const float denom = (mx - mn) + 1e-5f;

  // perturbed value for own index (bit-identical expression order)
  const uint32_t j = (uint32_t)(b * (NSAMP * DDIM) + n * DDIM + d);
  uint32_t o0, o1;
  threefry2x32_0_42(0u, j, o0, o1);
  const uint32_t bits = o0 ^ o1;
  const float flo = -0.99999994f;  // nextafter(-1,0) in f32
  float f = __uint_as_float((bits >> 9) | 0x3f800000u) - 1.0f;
  float u = f * 2.0f + flo;
  u = fmaxf(flo, u);
  const float z = 1.41421356237f * xla_erfinv(u);
  const float sv = (sc - mn) / denom;
  const float pv = sv + z * 0.05f;

  // monotone key: pv_a > pv_b <=> mk_a > mk_b (no NaNs here); ties broken by
  // smaller index getting the LARGER key => counts toward later dup's rank,
  // exactly jax.lax.top_k's stable behavior.
  const uint32_t pu = __float_as_uint(pv);
  const uint32_t mk = (pu & 0x80000000u) ? ~pu : (pu | 0x80000000u);
  const unsigned long long key =
      ((unsigned long long)mk << 32) | (unsigned long long)(255 - d);
  pk[d] = key;
  __syncthreads();

  int rank = 0;
  const ulonglong2* pk2 = (const ulonglong2*)pk;
  for (int e2 = 0; e2 < DDIM / 2; ++e2) {
    ulonglong2 kk = pk2[e2];          // broadcast b128 read
    rank += (kk.x > key);
    rank += (kk.y > key);
  }
  const bool sel = rank < 16;

  // rank among selected, ordered by ascending index (the jnp.sort step)
  const unsigned long long m = __ballot(sel);
  if (lane == 0) wtot[wv] = __popcll(m);
  __syncthreads();
  int r = __popcll(m & ((1ull << lane) - 1ull));
  for (int w2 = 0; w2 < wv; ++w2) r += wtot[w2];

  if (sel) atomicAdd(&counts[(b << 12) + (r << 8) + d], 1u);
}

// grid: (16 p-tiles, 3 c, 8 b); block 256 = 32 q-groups x 8 rows.
// ALL 16 k's per block: each x float4 is loaded once per (b,c,ptile) and
// FMA'd into 16 accumulators — halves L2/LLC x traffic vs 8-k blocks.
// Branchless bounds masks + compacted union columns + 1-deep prefetch.
__global__ void __launch_bounds__(256, 3) patches_kernel(const float* __restrict__ x,
                                                         const uint32_t* __restrict__ counts,
                                                         float* __restrict__ out) {
  const int p0 = blockIdx.x << 3;     // 8 rows per block
  const int c  = blockIdx.y;
  const int b  = blockIdx.z;

  __shared__ __align__(16) float cw[DDIM * 16];  // compacted [pos][k], 16 KB
  __shared__ int colOff[DDIM];                   // compacted i*65536 + w*64
  __shared__ int wcnt[4];

  const int tid = threadIdx.x;
  const int lane = tid & 63, wvi = tid >> 6;

  // load weights (coalesced per k), compact active union columns ascending
  {
    float wreg[16];
    bool any = false;
#pragma unroll
    for (int kk = 0; kk < 16; ++kk) {
      float w = (float)counts[(b << 12) + (kk << 8) + tid] / 500.0f;
      wreg[kk] = w;
      any = any || (w != 0.0f);
    }
    unsigned long long m = __ballot(any);
    if (lane == 0) wcnt[wvi] = __popcll(m);
    __syncthreads();
    int base = 0;
    for (int w2 = 0; w2 < wvi; ++w2) base += wcnt[w2];
    if (any) {
      int pos = base + __popcll(m & ((1ull << lane) - 1ull));
      colOff[pos] = ((tid >> 4) << 16) | ((tid & 15) << 6);  // i*65536 + w*64
#pragma unroll
      for (int kk = 0; kk < 16; ++kk) cw[pos * 16 + kk] = wreg[kk];
    }
    __syncthreads();
  }
  const int nact = wcnt[0] + wcnt[1] + wcnt[2] + wcnt[3];

  const int q0   = (tid & 31) << 2;   // 0,4,...,124
  const int slot = tid >> 5;          // 0..7
  const int ps   = p0 + slot;

  // bounds masks: bit w of qm / bit i of ym says the float4 is in-bounds
  int qm = 0xFFFF, ym = 0xFFFF;
  if (q0 < 32) qm &= ~1;
  if (q0 > 92) qm &= ~0x8000;
  if (ps < 32) ym &= ~1;
  if (ps > 95) ym &= ~0x8000;
  const int baseOff = (ps - 32) * 1024 + q0 - 32;  // add colOff -> x offset

  float4 acc[16];
#pragma unroll
  for (int kk = 0; kk < 16; ++kk) acc[kk] = make_float4(0.f, 0.f, 0.f, 0.f);

  const float* xim = x + ((size_t)(b * 3 + c) << 20);  // 1024*1024 plane

  float4 xv = make_float4(0.f, 0.f, 0.f, 0.f);
  int okc = 0;
  if (nact > 0) {
    const int co = colOff[0];
    okc = (qm >> ((co >> 6) & 15)) & (ym >> (co >> 16)) & 1;
    xv = *(const float4*)(xim + (okc ? (baseOff + co) : 0));
  }

  for (int it = 0; it < nact; ++it) {
    // issue next x load before this iteration's FMAs (1-deep prefetch)
    const int itn = (it + 1 < nact) ? it + 1 : it;
    const int con = colOff[itn];
    const int okn = (qm >> ((con >> 6) & 15)) & (ym >> (con >> 16)) & 1;
    const float4 xn = *(const float4*)(xim + (okn ? (baseOff + con) : 0));

    float4 xc = xv;
    xc.x = okc ? xc.x : 0.0f;
    xc.y = okc ? xc.y : 0.0f;
    xc.z = okc ? xc.z : 0.0f;
    xc.w = okc ? xc.w : 0.0f;

    const float4 wa = *(const float4*)&cw[it * 16 + 0];   // ds_read_b128
    const float4 wb = *(const float4*)&cw[it * 16 + 4];
    const float4 wc = *(const float4*)&cw[it * 16 + 8];
    const float4 wd = *(const float4*)&cw[it * 16 + 12];

#define ACC_K(kk, wv_)                                            \
    { acc[kk].x += (wv_) * xc.x; acc[kk].y += (wv_) * xc.y;       \
      acc[kk].z += (wv_) * xc.z; acc[kk].w += (wv_) * xc.w; }
    ACC_K(0,  wa.x) ACC_K(1,  wa.y) ACC_K(2,  wa.z) ACC_K(3,  wa.w)
    ACC_K(4,  wb.x) ACC_K(5,  wb.y) ACC_K(6,  wb.z) ACC_K(7,  wb.w)
    ACC_K(8,  wc.x) ACC_K(9,  wc.y) ACC_K(10, wc.z) ACC_K(11, wc.w)
    ACC_K(12, wd.x) ACC_K(13, wd.y) ACC_K(14, wd.z) ACC_K(15, wd.w)
#undef ACC_K

    xv = xn;
    okc = okn;
  }

#pragma unroll
  for (int kk = 0; kk < 16; ++kk) {
    const size_t obase = ((size_t)((b * 16 + kk) * 3 + c)) << 14;  // 128*128
    float4* dst = (float4*)(out + obase + (size_t)ps * 128 + q0);
    __builtin_nontemporal_store(acc[kk].x, &dst->x);
    __builtin_nontemporal_store(acc[kk].y, &dst->y);
    __builtin_nontemporal_store(acc[kk].z, &dst->z);
    __builtin_nontemporal_store(acc[kk].w, &dst->w);
  }
}

extern "C" void kernel_launch(void* const* d_in, const int* in_sizes, int n_in,
                              void* d_out, int out_size, void* d_ws, size_t ws_size,
                              hipStream_t stream) {
  const float* x_high = (const float*)d_in[0];
  const float* scores = (const float*)d_in[1];
  float* out = (float*)d_out;
  uint32_t* counts = (uint32_t*)d_ws;  // 8*16*256 u32 = 128 KB

  hipMemsetAsync(counts, 0, 8 * 16 * DDIM * sizeof(uint32_t), stream);
  topk_kernel<<<8 * NSAMP, 256, 0, stream>>>(scores, counts);
  patches_kernel<<<dim3(16, 3, 8), 256, 0, stream>>>(x_high, counts, out);
}